// Round 4
// baseline (74.652 us; speedup 1.0000x reference)
//
#include <hip/hip_runtime.h>

#define PI_HALF_F 1.57079632679489661923f

// ---- lane-exchange primitives ----
template<int CTRL>
__device__ __forceinline__ float dpp1(float v) {
    return __int_as_float(__builtin_amdgcn_update_dpp(
        0, __float_as_int(v), CTRL, 0xF, 0xF, true));
}
#define QP_XOR1   0xB1   // quad_perm [1,0,3,2]
#define QP_XOR2   0x4E   // quad_perm [2,3,0,1]
#define QP_XOR3   0x1B   // quad_perm [3,2,1,0]
#define ROW_ROR4  0x124
#define ROW_ROR8  0x128

template<int MASK>
__device__ __forceinline__ float swz(float v) {
    return __int_as_float(__builtin_amdgcn_ds_swizzle(
        __float_as_int(v), (MASK << 10) | 0x1F));
}

// exact xor-MASK exchange within 16-lane rows: DPP for intra-quad, DS swizzle for >=4
template<int MASK>
__device__ __forceinline__ float XL(float v) {
    if constexpr (MASK == 1)       return dpp1<QP_XOR1>(v);
    else if constexpr (MASK == 2)  return dpp1<QP_XOR2>(v);
    else if constexpr (MASK == 3)  return dpp1<QP_XOR3>(v);
    else                           return swz<MASK>(v);   // 4, 6, 8, 12
}

// ---- cross-lane 2x2 gate on TWO states, partner = lane ^ MASK ----
template<int MASK>
__device__ __forceinline__ void lane_gate2(float (&reA)[16], float (&imA)[16],
                                           float (&reB)[16], float (&imB)[16],
                                           float car, float cai, float cbr, float cbi) {
#pragma unroll
    for (int r = 0; r < 16; ++r) {
        const float arA = reA[r], aiA = imA[r];
        const float arB = reB[r], aiB = imB[r];
        const float brA = XL<MASK>(arA), biA = XL<MASK>(aiA);
        const float brB = XL<MASK>(arB), biB = XL<MASK>(aiB);
        reA[r] = car * arA - cai * aiA + cbr * brA - cbi * biA;
        imA[r] = car * aiA + cai * arA + cbr * biA + cbi * brA;
        reB[r] = car * arB - cai * aiB + cbr * brB - cbi * biB;
        imB[r] = car * aiB + cai * arB + cbr * biB + cbi * brB;
    }
}

// ---- in-register 2x2 gate on TWO states: pairs (r, r^MASK); hi = parity(r & FBITS)
template<int MASK, int FBITS>
__device__ __forceinline__ void reg_gate2(float (&reA)[16], float (&imA)[16],
        float (&reB)[16], float (&imB)[16],
        float c0r, float c0i, float d0r, float d0i,
        float c1r, float c1i, float d1r, float d1i) {
    constexpr int MSB = (MASK & 8) ? 8 : (MASK & 4) ? 4 : (MASK & 2) ? 2 : 1;
#pragma unroll
    for (int r = 0; r < 16; ++r) {
        if (r & MSB) continue;
        const int p = r ^ MASK;
        const bool f = __builtin_popcount(r & FBITS) & 1;  // compile-time
        const float sAr = f ? c1r : c0r, sAi = f ? c1i : c0i;
        const float tAr = f ? d1r : d0r, tAi = f ? d1i : d0i;
        const float sBr = f ? c0r : c1r, sBi = f ? c0i : c1i;
        const float tBr = f ? d0r : d1r, tBi = f ? d0i : d1i;
        {
            const float ar = reA[r], ai = imA[r], br = reA[p], bi = imA[p];
            reA[r] = sAr * ar - sAi * ai + tAr * br - tAi * bi;
            imA[r] = sAr * ai + sAi * ar + tAr * bi + tAi * br;
            reA[p] = sBr * br - sBi * bi + tBr * ar - tBi * ai;
            imA[p] = sBr * bi + sBi * br + tBr * ai + tBi * ar;
        }
        {
            const float ar = reB[r], ai = imB[r], br = reB[p], bi = imB[p];
            reB[r] = sAr * ar - sAi * ai + tAr * br - tAi * bi;
            imB[r] = sAr * ai + sAi * ar + tAr * bi + tAi * br;
            reB[p] = sBr * br - sBi * bi + tBr * ar - tBi * ai;
            imB[p] = sBr * bi + sBi * br + tBr * ai + tBi * ar;
        }
    }
}

__global__ __launch_bounds__(256) void quantum_kernel(
    const float* __restrict__ x,
    const float* __restrict__ theta,
    float* __restrict__ out,
    int B)
{
    // ---- per-block: 16 shared Rot matrices in LDS ----
    __shared__ float g[16][8];
    const int t = threadIdx.x;
    if (t < 16) {
        const int layer = t >> 3, q = t & 7;
        const float phi = theta[(layer * 8 + q) * 3 + 0];
        const float th  = theta[(layer * 8 + q) * 3 + 1];
        const float om  = theta[(layer * 8 + q) * 3 + 2];
        const float ct = __cosf(0.5f * th), st = __sinf(0.5f * th);
        const float a = 0.5f * (phi + om), b = 0.5f * (phi - om);
        const float ca = __cosf(a), sa = __sinf(a);
        const float cb = __cosf(b), sb = __sinf(b);
        g[t][0] =  ct * ca;  g[t][1] = -ct * sa;
        g[t][2] = -st * cb;  g[t][3] = -st * sb;
        g[t][4] =  st * cb;  g[t][5] = -st * sb;
        g[t][6] =  ct * ca;  g[t][7] =  ct * sa;
    }
    __syncthreads();

    const int tid = blockIdx.x * 256 + t;
    const int group = tid >> 4;          // each 16-lane group: samples 2g, 2g+1
    const int sA = group * 2;
    if (sA >= B) return;
    const int sub = t & 15;

    // ---- encoding for both samples ----
    const float4* xpA = reinterpret_cast<const float4*>(x + sA * 8);
    const float4 xa0 = xpA[0], xa1 = xpA[1], xb0 = xpA[2], xb1 = xpA[3];
    float xsA[8] = {xa0.x, xa0.y, xa0.z, xa0.w, xa1.x, xa1.y, xa1.z, xa1.w};
    float xsB[8] = {xb0.x, xb0.y, xb0.z, xb0.w, xb1.x, xb1.y, xb1.z, xb1.w};

    float reA[16], imA[16], reB[16], imB[16];
    {
        float cqA[8], sqA[8], cqB[8], sqB[8];
#pragma unroll
        for (int q = 0; q < 8; ++q) {
            float vA = fminf(fmaxf(xsA[q], -1.0f), 1.0f) * PI_HALF_F;
            float vB = fminf(fmaxf(xsB[q], -1.0f), 1.0f) * PI_HALF_F;
            cqA[q] = __cosf(vA); sqA[q] = __sinf(vA);
            cqB[q] = __cosf(vB); sqB[q] = __sinf(vB);
        }
        const float planeA = ((sub & 8) ? sqA[0] : cqA[0]) * ((sub & 4) ? sqA[1] : cqA[1])
                           * ((sub & 2) ? sqA[2] : cqA[2]) * ((sub & 1) ? sqA[3] : cqA[3]);
        const float planeB = ((sub & 8) ? sqB[0] : cqB[0]) * ((sub & 4) ? sqB[1] : cqB[1])
                           * ((sub & 2) ? sqB[2] : cqB[2]) * ((sub & 1) ? sqB[3] : cqB[3]);
        float h45A[4], h67A[4], h45B[4], h67B[4];
#pragma unroll
        for (int k = 0; k < 4; ++k) {
            h45A[k] = ((k & 2) ? sqA[4] : cqA[4]) * ((k & 1) ? sqA[5] : cqA[5]) * planeA;
            h67A[k] = ((k & 2) ? sqA[6] : cqA[6]) * ((k & 1) ? sqA[7] : cqA[7]);
            h45B[k] = ((k & 2) ? sqB[4] : cqB[4]) * ((k & 1) ? sqB[5] : cqB[5]) * planeB;
            h67B[k] = ((k & 2) ? sqB[6] : cqB[6]) * ((k & 1) ? sqB[7] : cqB[7]);
        }
#pragma unroll
        for (int r = 0; r < 16; ++r) {
            reA[r] = h45A[r >> 2] * h67A[r & 3]; imA[r] = 0.0f;
            reB[r] = h45B[r >> 2] * h67B[r & 3]; imB[r] = 0.0f;
        }
    }

#define LOADG(idx) \
    const float4 ga = *reinterpret_cast<const float4*>(&g[idx][0]); \
    const float4 gb = *reinterpret_cast<const float4*>(&g[idx][4]); \
    const float u00r = ga.x, u00i = ga.y, u01r = ga.z, u01i = ga.w; \
    const float u10r = gb.x, u10i = gb.y, u11r = gb.z, u11i = gb.w;

#define LANE_COEFFS(hi) \
    const float car = (hi) ? u11r : u00r, cai = (hi) ? u11i : u00i; \
    const float cbr = (hi) ? u10r : u01r, cbi = (hi) ? u10i : u01i;

    const bool s3 = (sub >> 3) & 1, s2 = (sub >> 2) & 1, s1 = (sub >> 1) & 1, s0 = sub & 1;
    const bool par4 = s3 ^ s2 ^ s1 ^ s0;

    // ================= LAYER 1 (M = I) =================
    { LOADG(0); LANE_COEFFS(s3); lane_gate2<8>(reA, imA, reB, imB, car, cai, cbr, cbi); }
    { LOADG(1); LANE_COEFFS(s2); lane_gate2<4>(reA, imA, reB, imB, car, cai, cbr, cbi); }
    { LOADG(2); LANE_COEFFS(s1); lane_gate2<2>(reA, imA, reB, imB, car, cai, cbr, cbi); }
    { LOADG(3); LANE_COEFFS(s0); lane_gate2<1>(reA, imA, reB, imB, car, cai, cbr, cbi); }
    { LOADG(4); reg_gate2<8,8>(reA, imA, reB, imB, u00r,u00i, u01r,u01i, u11r,u11i, u10r,u10i); }
    { LOADG(5); reg_gate2<4,4>(reA, imA, reB, imB, u00r,u00i, u01r,u01i, u11r,u11i, u10r,u10i); }
    { LOADG(6); reg_gate2<2,2>(reA, imA, reB, imB, u00r,u00i, u01r,u01i, u11r,u11i, u10r,u10i); }
    { LOADG(7); reg_gate2<1,1>(reA, imA, reB, imB, u00r,u00i, u01r,u01i, u11r,u11i, u10r,u10i); }
    // CNOT chain: GF(2) relabel -> zero instructions.

    // ================= LAYER 2 (M = prefix) =================
    { LOADG(8);  LANE_COEFFS(s3);           lane_gate2<12>(reA, imA, reB, imB, car, cai, cbr, cbi); }
    { LOADG(9);  LANE_COEFFS(s3 ^ s2);      lane_gate2<6>(reA, imA, reB, imB, car, cai, cbr, cbi); }
    { LOADG(10); LANE_COEFFS(s3 ^ s2 ^ s1); lane_gate2<3>(reA, imA, reB, imB, car, cai, cbr, cbi); }
    // q3: partner = (lane^1, r^8); hi = par4
    {
        LOADG(11); LANE_COEFFS(par4);
#pragma unroll
        for (int r = 0; r < 8; ++r) {
            {
                const float a0r = reA[r],     a0i = imA[r];
                const float a1r = reA[r + 8], a1i = imA[r + 8];
                const float b0r = dpp1<QP_XOR1>(a1r), b0i = dpp1<QP_XOR1>(a1i);
                const float b1r = dpp1<QP_XOR1>(a0r), b1i = dpp1<QP_XOR1>(a0i);
                reA[r]     = car * a0r - cai * a0i + cbr * b0r - cbi * b0i;
                imA[r]     = car * a0i + cai * a0r + cbr * b0i + cbi * b0r;
                reA[r + 8] = car * a1r - cai * a1i + cbr * b1r - cbi * b1i;
                imA[r + 8] = car * a1i + cai * a1r + cbr * b1i + cbi * b1r;
            }
            {
                const float a0r = reB[r],     a0i = imB[r];
                const float a1r = reB[r + 8], a1i = imB[r + 8];
                const float b0r = dpp1<QP_XOR1>(a1r), b0i = dpp1<QP_XOR1>(a1i);
                const float b1r = dpp1<QP_XOR1>(a0r), b1i = dpp1<QP_XOR1>(a0i);
                reB[r]     = car * a0r - cai * a0i + cbr * b0r - cbi * b0i;
                imB[r]     = car * a0i + cai * a0r + cbr * b0i + cbi * b0r;
                reB[r + 8] = car * a1r - cai * a1i + cbr * b1r - cbi * b1i;
                imB[r + 8] = car * a1i + cai * a1r + cbr * b1i + cbi * b1r;
            }
        }
    }
#define REG2_COEFFS() \
    const float c0r = par4 ? u11r : u00r, c0i = par4 ? u11i : u00i; \
    const float d0r = par4 ? u10r : u01r, d0i = par4 ? u10i : u01i; \
    const float c1r = par4 ? u00r : u11r, c1i = par4 ? u00i : u11i; \
    const float d1r = par4 ? u01r : u10r, d1i = par4 ? u01i : u10i;
    { LOADG(12); REG2_COEFFS(); reg_gate2<12,8>(reA, imA, reB, imB, c0r,c0i,d0r,d0i,c1r,c1i,d1r,d1i); }
    { LOADG(13); REG2_COEFFS(); reg_gate2<6,12>(reA, imA, reB, imB, c0r,c0i,d0r,d0i,c1r,c1i,d1r,d1i); }
    { LOADG(14); REG2_COEFFS(); reg_gate2<3,14>(reA, imA, reB, imB, c0r,c0i,d0r,d0i,c1r,c1i,d1r,d1i); }
    { LOADG(15); REG2_COEFFS(); reg_gate2<1,15>(reA, imA, reB, imB, c0r,c0i,d0r,d0i,c1r,c1i,d1r,d1i); }

    // ================= measurement under final M =================
    const bool sgnA_ = s3 ^ s1;  // p0^p2
    const bool sgnB_ = s2 ^ s0;  // p1^p3

#define MEASURE(re_, im_, z0,z1,z2,z3,z4,z5,z6,z7) \
    float A_ = 0.f, B3_ = 0.f, B2_ = 0.f, B31_ = 0.f, B20_ = 0.f; \
    _Pragma("unroll") \
    for (int r = 0; r < 16; ++r) { \
        const float P = re_[r] * re_[r] + im_[r] * im_[r]; \
        A_   += P; \
        B3_  += (r & 8) ? -P : P; \
        B2_  += (r & 4) ? -P : P; \
        B31_ += ((((r >> 3) ^ (r >> 1)) & 1) ? -P : P); \
        B20_ += ((((r >> 2) ^ r) & 1) ? -P : P); \
    } \
    float z0 = s3    ? -A_   : A_; \
    float z1 = s2    ? -A_   : A_; \
    float z2 = sgnA_ ? -A_   : A_; \
    float z3 = sgnB_ ? -A_   : A_; \
    float z4 = sgnA_ ? -B3_  : B3_; \
    float z5 = sgnB_ ? -B2_  : B2_; \
    float z6 = sgnA_ ? -B31_ : B31_; \
    float z7 = sgnB_ ? -B20_ : B20_;

#define RED(z) \
    z += dpp1<QP_XOR1>(z); z += dpp1<QP_XOR2>(z); \
    z += dpp1<ROW_ROR4>(z); z += dpp1<ROW_ROR8>(z);

    float vA, vB;
    {
        MEASURE(reA, imA, zA0, zA1, zA2, zA3, zA4, zA5, zA6, zA7)
        RED(zA0) RED(zA1) RED(zA2) RED(zA3) RED(zA4) RED(zA5) RED(zA6) RED(zA7)
        const int i = sub & 7;
        float v = zA0;
        v = (i == 1) ? zA1 : v; v = (i == 2) ? zA2 : v; v = (i == 3) ? zA3 : v;
        v = (i == 4) ? zA4 : v; v = (i == 5) ? zA5 : v; v = (i == 6) ? zA6 : v;
        v = (i == 7) ? zA7 : v;
        vA = v;
    }
    {
        MEASURE(reB, imB, zB0, zB1, zB2, zB3, zB4, zB5, zB6, zB7)
        RED(zB0) RED(zB1) RED(zB2) RED(zB3) RED(zB4) RED(zB5) RED(zB6) RED(zB7)
        const int i = sub & 7;
        float v = zB0;
        v = (i == 1) ? zB1 : v; v = (i == 2) ? zB2 : v; v = (i == 3) ? zB3 : v;
        v = (i == 4) ? zB4 : v; v = (i == 5) ? zB5 : v; v = (i == 6) ? zB6 : v;
        v = (i == 7) ? zB7 : v;
        vB = v;
    }
    // coalesced 16-float store per group: lanes 0-7 -> sample A, 8-15 -> sample B
    out[group * 16 + sub] = (sub < 8) ? vA : vB;
}

extern "C" void kernel_launch(void* const* d_in, const int* in_sizes, int n_in,
                              void* d_out, int out_size, void* d_ws, size_t ws_size,
                              hipStream_t stream) {
    const float* x     = (const float*)d_in[0];
    const float* theta = (const float*)d_in[1];
    float* out = (float*)d_out;
    const int B = in_sizes[0] / 8;
    const int threads_total = (B / 2) * 16;   // 16 lanes per 2 samples
    const int blocks = (threads_total + 255) / 256;
    hipLaunchKernelGGL(quantum_kernel, dim3(blocks), dim3(256), 0, stream,
                       x, theta, out, B);
}

// Round 5
// 70.325 us; speedup vs baseline: 1.0615x; 1.0615x over previous
//
#include <hip/hip_runtime.h>

#define PI_HALF_F 1.57079632679489661923f

// ---- lane-exchange primitives ----
template<int CTRL>
__device__ __forceinline__ float dpp1(float v) {
    return __int_as_float(__builtin_amdgcn_update_dpp(
        0, __float_as_int(v), CTRL, 0xF, 0xF, true));
}
#define QP_XOR1   0xB1   // quad_perm [1,0,3,2]
#define QP_XOR2   0x4E   // quad_perm [2,3,0,1]
#define QP_XOR3   0x1B   // quad_perm [3,2,1,0]
#define ROW_ROR4  0x124
#define ROW_ROR8  0x128

template<int MASK>
__device__ __forceinline__ float swz(float v) {
    return __int_as_float(__builtin_amdgcn_ds_swizzle(
        __float_as_int(v), (MASK << 10) | 0x1F));
}

// exact xor-MASK exchange within 32-lane halves: DPP intra-quad, DS swizzle >=4
template<int MASK>
__device__ __forceinline__ float XL(float v) {
    if constexpr (MASK == 1)       return dpp1<QP_XOR1>(v);
    else if constexpr (MASK == 2)  return dpp1<QP_XOR2>(v);
    else if constexpr (MASK == 3)  return dpp1<QP_XOR3>(v);
    else                           return swz<MASK>(v);   // 4,6,8,12,16,24
}

// ---- cross-lane 2x2 gate on 8 amps, partner = lane ^ MASK ----
template<int MASK>
__device__ __forceinline__ void lane_gate(float (&re)[8], float (&im)[8],
                                          float car, float cai, float cbr, float cbi) {
#pragma unroll
    for (int r = 0; r < 8; ++r) {
        const float ar = re[r], ai = im[r];
        const float br = XL<MASK>(ar), bi = XL<MASK>(ai);
        re[r] = car * ar - cai * ai + cbr * br - cbi * bi;
        im[r] = car * ai + cai * ar + cbr * bi + cbi * br;
    }
}

// ---- in-register 2x2 gate: pairs (r, r^MASK), r in [0,8); hi = parity(r & FBITS)
template<int MASK, int FBITS>
__device__ __forceinline__ void reg_gate(float (&re)[8], float (&im)[8],
        float c0r, float c0i, float d0r, float d0i,
        float c1r, float c1i, float d1r, float d1i) {
    constexpr int MSB = (MASK & 4) ? 4 : (MASK & 2) ? 2 : 1;
#pragma unroll
    for (int r = 0; r < 8; ++r) {
        if (r & MSB) continue;
        const int p = r ^ MASK;
        const bool f = __builtin_popcount(r & FBITS) & 1;  // compile-time
        const float sAr = f ? c1r : c0r, sAi = f ? c1i : c0i;
        const float tAr = f ? d1r : d0r, tAi = f ? d1i : d0i;
        const float sBr = f ? c0r : c1r, sBi = f ? c0i : c1i;
        const float tBr = f ? d0r : d1r, tBi = f ? d0i : d1i;
        const float ar = re[r], ai = im[r], br = re[p], bi = im[p];
        re[r] = sAr * ar - sAi * ai + tAr * br - tAi * bi;
        im[r] = sAr * ai + sAi * ar + tAr * bi + tAi * br;
        re[p] = sBr * br - sBi * bi + tBr * ar - tBi * ai;
        im[p] = sBr * bi + sBi * br + tBr * ai + tBi * ar;
    }
}

__global__ __launch_bounds__(256, 8) void quantum_kernel(
    const float* __restrict__ x,
    const float* __restrict__ theta,
    float* __restrict__ out,
    int B)
{
    // ---- per-block: 16 shared Rot matrices in LDS ----
    __shared__ float g[16][8];  // [layer*8+q][u00r,u00i,u01r,u01i,u10r,u10i,u11r,u11i]
    const int t = threadIdx.x;
    if (t < 16) {
        const int layer = t >> 3, q = t & 7;
        const float phi = theta[(layer * 8 + q) * 3 + 0];
        const float th  = theta[(layer * 8 + q) * 3 + 1];
        const float om  = theta[(layer * 8 + q) * 3 + 2];
        const float ct = __cosf(0.5f * th), st = __sinf(0.5f * th);
        const float a = 0.5f * (phi + om), b = 0.5f * (phi - om);
        const float ca = __cosf(a), sa = __sinf(a);
        const float cb = __cosf(b), sb = __sinf(b);
        g[t][0] =  ct * ca;  g[t][1] = -ct * sa;
        g[t][2] = -st * cb;  g[t][3] = -st * sb;
        g[t][4] =  st * cb;  g[t][5] = -st * sb;
        g[t][6] =  ct * ca;  g[t][7] =  ct * sa;
    }
    __syncthreads();

    const int tid = blockIdx.x * 256 + t;
    const int sample = tid >> 5;       // 32 lanes per sample
    if (sample >= B) return;
    const int sub = t & 31;            // lane bits b4..b0 <-> qubits 0..4

    const bool b4 = (sub >> 4) & 1, b3 = (sub >> 3) & 1, b2 = (sub >> 2) & 1;
    const bool b1 = (sub >> 1) & 1, b0 = sub & 1;
    const bool par5 = b4 ^ b3 ^ b2 ^ b1 ^ b0;

    // ---- encoding: product state after RY(pi*x); qubits 5-7 in reg bits r2..r0 ----
    float re[8], im[8];
    {
        const float4* xp = reinterpret_cast<const float4*>(x + sample * 8);
        const float4 xa = xp[0], xb = xp[1];
        const float xs[8] = {xa.x, xa.y, xa.z, xa.w, xb.x, xb.y, xb.z, xb.w};
        float cq[8], sq[8];
#pragma unroll
        for (int q = 0; q < 8; ++q) {
            const float v = fminf(fmaxf(xs[q], -1.0f), 1.0f) * PI_HALF_F;
            cq[q] = __cosf(v);
            sq[q] = __sinf(v);
        }
        const float plane = (b4 ? sq[0] : cq[0]) * (b3 ? sq[1] : cq[1])
                          * (b2 ? sq[2] : cq[2]) * (b1 ? sq[3] : cq[3])
                          * (b0 ? sq[4] : cq[4]);
        const float h5l = plane * cq[5], h5h = plane * sq[5];
        float h67[4];
#pragma unroll
        for (int k = 0; k < 4; ++k)
            h67[k] = ((k & 2) ? sq[6] : cq[6]) * ((k & 1) ? sq[7] : cq[7]);
#pragma unroll
        for (int r = 0; r < 8; ++r) {
            re[r] = ((r & 4) ? h5h : h5l) * h67[r & 3];
            im[r] = 0.0f;
        }
    }

#define LOADG(idx) \
    const float4 ga = *reinterpret_cast<const float4*>(&g[idx][0]); \
    const float4 gb = *reinterpret_cast<const float4*>(&g[idx][4]); \
    const float u00r = ga.x, u00i = ga.y, u01r = ga.z, u01i = ga.w; \
    const float u10r = gb.x, u10i = gb.y, u11r = gb.z, u11i = gb.w;

#define LANE_COEFFS(hi) \
    const float car = (hi) ? u11r : u00r, cai = (hi) ? u11i : u00i; \
    const float cbr = (hi) ? u10r : u01r, cbi = (hi) ? u10i : u01i;

    // ================= LAYER 1 (M = I) =================
    { LOADG(0); LANE_COEFFS(b4); lane_gate<16>(re, im, car, cai, cbr, cbi); }
    { LOADG(1); LANE_COEFFS(b3); lane_gate<8>(re, im, car, cai, cbr, cbi); }
    { LOADG(2); LANE_COEFFS(b2); lane_gate<4>(re, im, car, cai, cbr, cbi); }
    { LOADG(3); LANE_COEFFS(b1); lane_gate<2>(re, im, car, cai, cbr, cbi); }
    { LOADG(4); LANE_COEFFS(b0); lane_gate<1>(re, im, car, cai, cbr, cbi); }
    { LOADG(5); reg_gate<4,4>(re, im, u00r,u00i, u01r,u01i, u11r,u11i, u10r,u10i); }
    { LOADG(6); reg_gate<2,2>(re, im, u00r,u00i, u01r,u01i, u11r,u11i, u10r,u10i); }
    { LOADG(7); reg_gate<1,1>(re, im, u00r,u00i, u01r,u01i, u11r,u11i, u10r,u10i); }
    // CNOT chain: GF(2) relabel -> zero instructions.

    // ================= LAYER 2 (M = prefix) =================
    // gate q pairs differ by delta = e_q ^ e_{q+1}; hi = prefix parity p0..pq
    { LOADG(8);  LANE_COEFFS(b4);                lane_gate<24>(re, im, car, cai, cbr, cbi); }
    { LOADG(9);  LANE_COEFFS(b4 ^ b3);           lane_gate<12>(re, im, car, cai, cbr, cbi); }
    { LOADG(10); LANE_COEFFS(b4 ^ b3 ^ b2);      lane_gate<6>(re, im, car, cai, cbr, cbi); }
    { LOADG(11); LANE_COEFFS(b4 ^ b3 ^ b2 ^ b1); lane_gate<3>(re, im, car, cai, cbr, cbi); }
    // q4: partner = (lane^1, r^4); hi = par5 (uniform over regs)
    {
        LOADG(12); LANE_COEFFS(par5);
#pragma unroll
        for (int r = 0; r < 4; ++r) {
            const float a0r = re[r],     a0i = im[r];
            const float a1r = re[r + 4], a1i = im[r + 4];
            const float p0r = dpp1<QP_XOR1>(a1r), p0i = dpp1<QP_XOR1>(a1i);
            const float p1r = dpp1<QP_XOR1>(a0r), p1i = dpp1<QP_XOR1>(a0i);
            re[r]     = car * a0r - cai * a0i + cbr * p0r - cbi * p0i;
            im[r]     = car * a0i + cai * a0r + cbr * p0i + cbi * p0r;
            re[r + 4] = car * a1r - cai * a1i + cbr * p1r - cbi * p1i;
            im[r + 4] = car * a1i + cai * a1r + cbr * p1i + cbi * p1r;
        }
    }
    // q5..q7: in-register, element hi = par5 ^ parity(r & FBITS)
#define REG2_COEFFS() \
    const float c0r = par5 ? u11r : u00r, c0i = par5 ? u11i : u00i; \
    const float d0r = par5 ? u10r : u01r, d0i = par5 ? u10i : u01i; \
    const float c1r = par5 ? u00r : u11r, c1i = par5 ? u00i : u11i; \
    const float d1r = par5 ? u01r : u10r, d1i = par5 ? u01i : u10i;
    { LOADG(13); REG2_COEFFS(); reg_gate<6,4>(re, im, c0r,c0i,d0r,d0i,c1r,c1i,d1r,d1i); }
    { LOADG(14); REG2_COEFFS(); reg_gate<3,6>(re, im, c0r,c0i,d0r,d0i,c1r,c1i,d1r,d1i); }
    { LOADG(15); REG2_COEFFS(); reg_gate<1,7>(re, im, c0r,c0i,d0r,d0i,c1r,c1i,d1r,d1i); }

    // ================= measurement under final M =================
    // M0=p0 M1=p1 M2=p0^p2 M3=p1^p3 M4=p0^p2^p4 M5=p1^p3^p5 M6=p0^p2^p4^p6 M7=p1^p3^p5^p7
    // p0..p4 = lane bits b4..b0 ; p5,p6,p7 = reg bits r2,r1,r0
    float P[8];
#pragma unroll
    for (int r = 0; r < 8; ++r) P[r] = re[r] * re[r] + im[r] * im[r];

    const float t01 = P[0] + P[1], t23 = P[2] + P[3];
    const float t45 = P[4] + P[5], t67 = P[6] + P[7];
    const float A  = (t01 + t23) + (t45 + t67);
    const float B5 = (t01 + t23) - (t45 + t67);                 // (-1)^{r2}
    const float B6 = (t01 - t23) + (t45 - t67);                 // (-1)^{r1}
    const float B7 = (P[0] - P[1]) + (P[2] - P[3])
                   - (P[4] - P[5]) - (P[6] - P[7]);             // (-1)^{r2^r0}

    const bool gOdd  = b3 ^ b1;          // p1^p3
    const bool gEven = b4 ^ b2;          // p0^p2
    const bool gEv0  = gEven ^ b0;       // p0^p2^p4
    float z0 = b4    ? -A  : A;
    float z1 = b3    ? -A  : A;
    float z2 = gEven ? -A  : A;
    float z3 = gOdd  ? -A  : A;
    float z4 = gEv0  ? -A  : A;
    float z5 = gOdd  ? -B5 : B5;
    float z6 = gEv0  ? -B6 : B6;
    float z7 = gOdd  ? -B7 : B7;

    // butterfly over the 32-lane half-wave
#define RED(z) \
    z += dpp1<QP_XOR1>(z); z += dpp1<QP_XOR2>(z); \
    z += dpp1<ROW_ROR4>(z); z += dpp1<ROW_ROR8>(z); \
    z += swz<16>(z);
    RED(z0) RED(z1) RED(z2) RED(z3) RED(z4) RED(z5) RED(z6) RED(z7)
#undef RED

    if (sub < 8) {
        float v = z0;
        v = (sub == 1) ? z1 : v;
        v = (sub == 2) ? z2 : v;
        v = (sub == 3) ? z3 : v;
        v = (sub == 4) ? z4 : v;
        v = (sub == 5) ? z5 : v;
        v = (sub == 6) ? z6 : v;
        v = (sub == 7) ? z7 : v;
        out[sample * 8 + sub] = v;
    }
}

extern "C" void kernel_launch(void* const* d_in, const int* in_sizes, int n_in,
                              void* d_out, int out_size, void* d_ws, size_t ws_size,
                              hipStream_t stream) {
    const float* x     = (const float*)d_in[0];
    const float* theta = (const float*)d_in[1];
    float* out = (float*)d_out;
    const int B = in_sizes[0] / 8;
    const long long threads_total = (long long)B * 32;   // 32 lanes per sample
    const int blocks = (int)((threads_total + 255) / 256);
    hipLaunchKernelGGL(quantum_kernel, dim3(blocks), dim3(256), 0, stream,
                       x, theta, out, B);
}

// Round 6
// 64.765 us; speedup vs baseline: 1.1527x; 1.0858x over previous
//
#include <hip/hip_runtime.h>

#define PI_HALF_F 1.57079632679489661923f

// ---- lane-exchange primitives ----
template<int CTRL>
__device__ __forceinline__ float dpp1(float v) {
    return __int_as_float(__builtin_amdgcn_update_dpp(
        0, __float_as_int(v), CTRL, 0xF, 0xF, true));
}
#define QP_XOR1   0xB1   // quad_perm [1,0,3,2]
#define QP_XOR2   0x4E   // quad_perm [2,3,0,1]
#define QP_XOR3   0x1B   // quad_perm [3,2,1,0]
#define ROW_ROR4  0x124
#define ROW_ROR8  0x128

template<int MASK>
__device__ __forceinline__ float swz(float v) {
    return __int_as_float(__builtin_amdgcn_ds_swizzle(
        __float_as_int(v), (MASK << 10) | 0x1F));
}

// exact xor-MASK exchange within 32-lane halves: DPP intra-quad, DS swizzle >=4
template<int MASK>
__device__ __forceinline__ float XL(float v) {
    if constexpr (MASK == 1)       return dpp1<QP_XOR1>(v);
    else if constexpr (MASK == 2)  return dpp1<QP_XOR2>(v);
    else if constexpr (MASK == 3)  return dpp1<QP_XOR3>(v);
    else                           return swz<MASK>(v);   // 4,6,8,12,16,24
}

// ---- cross-lane 2x2 gate on 8 amps, partner = lane ^ MASK ----
template<int MASK>
__device__ __forceinline__ void lane_gate(float (&re)[8], float (&im)[8],
                                          float car, float cai, float cbr, float cbi) {
#pragma unroll
    for (int r = 0; r < 8; ++r) {
        const float ar = re[r], ai = im[r];
        const float br = XL<MASK>(ar), bi = XL<MASK>(ai);
        re[r] = car * ar - cai * ai + cbr * br - cbi * bi;
        im[r] = car * ai + cai * ar + cbr * bi + cbi * br;
    }
}

// ---- in-register 2x2 gate: pairs (r, r^MASK), r in [0,8); hi = parity(r & FBITS)
template<int MASK, int FBITS>
__device__ __forceinline__ void reg_gate(float (&re)[8], float (&im)[8],
        float c0r, float c0i, float d0r, float d0i,
        float c1r, float c1i, float d1r, float d1i) {
    constexpr int MSB = (MASK & 4) ? 4 : (MASK & 2) ? 2 : 1;
#pragma unroll
    for (int r = 0; r < 8; ++r) {
        if (r & MSB) continue;
        const int p = r ^ MASK;
        const bool f = __builtin_popcount(r & FBITS) & 1;  // compile-time
        const float sAr = f ? c1r : c0r, sAi = f ? c1i : c0i;
        const float tAr = f ? d1r : d0r, tAi = f ? d1i : d0i;
        const float sBr = f ? c0r : c1r, sBi = f ? c0i : c1i;
        const float tBr = f ? d0r : d1r, tBi = f ? d0i : d1i;
        const float ar = re[r], ai = im[r], br = re[p], bi = im[p];
        re[r] = sAr * ar - sAi * ai + tAr * br - tAi * bi;
        im[r] = sAr * ai + sAi * ar + tAr * bi + tAi * br;
        re[p] = sBr * br - sBi * bi + tBr * ar - tBi * ai;
        im[p] = sBr * bi + sBi * br + tBr * ai + tBi * ar;
    }
}

__global__ __launch_bounds__(256, 8) void quantum_kernel(
    const float* __restrict__ x,
    const float* __restrict__ theta,
    float* __restrict__ out,
    int B)
{
    // ---- per-block: 16 shared Rot matrices in LDS ----
    __shared__ float g[16][8];  // [layer*8+q][u00r,u00i,u01r,u01i,u10r,u10i,u11r,u11i]
    const int t = threadIdx.x;
    if (t < 16) {
        const int layer = t >> 3, q = t & 7;
        const float phi = theta[(layer * 8 + q) * 3 + 0];
        const float th  = theta[(layer * 8 + q) * 3 + 1];
        const float om  = theta[(layer * 8 + q) * 3 + 2];
        const float ct = __cosf(0.5f * th), st = __sinf(0.5f * th);
        const float a = 0.5f * (phi + om), b = 0.5f * (phi - om);
        const float ca = __cosf(a), sa = __sinf(a);
        const float cb = __cosf(b), sb = __sinf(b);
        g[t][0] =  ct * ca;  g[t][1] = -ct * sa;
        g[t][2] = -st * cb;  g[t][3] = -st * sb;
        g[t][4] =  st * cb;  g[t][5] = -st * sb;
        g[t][6] =  ct * ca;  g[t][7] =  ct * sa;
    }
    __syncthreads();

    const int tid = blockIdx.x * 256 + t;
    const int sample = tid >> 5;       // 32 lanes per sample
    if (sample >= B) return;
    const int sub = t & 31;            // lane bits b4..b0 <-> qubits 0..4

    const bool b4 = (sub >> 4) & 1, b3 = (sub >> 3) & 1, b2 = (sub >> 2) & 1;
    const bool b1 = (sub >> 1) & 1, b0 = sub & 1;
    const bool par5 = b4 ^ b3 ^ b2 ^ b1 ^ b0;

    // ---- FUSED: encoding RY + ALL of layer-1 Rot -> complex product state ----
    // Per qubit q: factor v_q = U1_q . (c_q, s_q)^T  (complex 2-vector).
    // amp(idx) = prod_q v_q[bit_q(idx)];  qubits 0..4 <-> lane bits b4..b0,
    // qubits 5,6,7 <-> reg bits r2,r1,r0.
    float re[8], im[8];
    {
        const float4* xp = reinterpret_cast<const float4*>(x + sample * 8);
        const float4 xa = xp[0], xb = xp[1];
        const float xs[8] = {xa.x, xa.y, xa.z, xa.w, xb.x, xb.y, xb.z, xb.w};
        float cq[8], sq[8];
#pragma unroll
        for (int q = 0; q < 8; ++q) {
            const float v = fminf(fmaxf(xs[q], -1.0f), 1.0f) * PI_HALF_F;
            cq[q] = __cosf(v);
            sq[q] = __sinf(v);
        }
        float wrr[5], wri[5];                  // selected component, lane qubits 0..4
        float v5r[2], v5i[2], v6r[2], v6i[2], v7r[2], v7i[2];
#pragma unroll
        for (int q = 0; q < 8; ++q) {
            const float4 ga = *reinterpret_cast<const float4*>(&g[q][0]);
            const float4 gb = *reinterpret_cast<const float4*>(&g[q][4]);
            const float c = cq[q], s = sq[q];
            const float v0r = ga.x * c + ga.z * s, v0i = ga.y * c + ga.w * s;
            const float v1r = gb.x * c + gb.z * s, v1i = gb.y * c + gb.w * s;
            if (q < 5) {
                const bool bit = (sub >> (4 - q)) & 1;
                wrr[q] = bit ? v1r : v0r;
                wri[q] = bit ? v1i : v0i;
            } else if (q == 5) {
                v5r[0] = v0r; v5i[0] = v0i; v5r[1] = v1r; v5i[1] = v1i;
            } else if (q == 6) {
                v6r[0] = v0r; v6i[0] = v0i; v6r[1] = v1r; v6i[1] = v1i;
            } else {
                v7r[0] = v0r; v7i[0] = v0i; v7r[1] = v1r; v7i[1] = v1i;
            }
        }
        // plane = w0*w1*w2*w3*w4 (complex)
        float pr = wrr[0], pi_ = wri[0];
#pragma unroll
        for (int q = 1; q < 5; ++q) {
            const float nr = pr * wrr[q] - pi_ * wri[q];
            const float ni = pr * wri[q] + pi_ * wrr[q];
            pr = nr; pi_ = ni;
        }
        // ph5[k] = plane * v5[k]
        float p5r[2], p5i[2];
#pragma unroll
        for (int k = 0; k < 2; ++k) {
            p5r[k] = pr * v5r[k] - pi_ * v5i[k];
            p5i[k] = pr * v5i[k] + pi_ * v5r[k];
        }
        // h67[k] = v6[k>>1] * v7[k&1]
        float h67r[4], h67i[4];
#pragma unroll
        for (int k = 0; k < 4; ++k) {
            h67r[k] = v6r[k >> 1] * v7r[k & 1] - v6i[k >> 1] * v7i[k & 1];
            h67i[k] = v6r[k >> 1] * v7i[k & 1] + v6i[k >> 1] * v7r[k & 1];
        }
        // amp[r] = ph5[r>>2] * h67[r&3]
#pragma unroll
        for (int r = 0; r < 8; ++r) {
            re[r] = p5r[r >> 2] * h67r[r & 3] - p5i[r >> 2] * h67i[r & 3];
            im[r] = p5r[r >> 2] * h67i[r & 3] + p5i[r >> 2] * h67r[r & 3];
        }
    }
    // layer-1 CNOT chain: GF(2) relabel -> zero instructions.

#define LOADG(idx) \
    const float4 ga = *reinterpret_cast<const float4*>(&g[idx][0]); \
    const float4 gb = *reinterpret_cast<const float4*>(&g[idx][4]); \
    const float u00r = ga.x, u00i = ga.y, u01r = ga.z, u01i = ga.w; \
    const float u10r = gb.x, u10i = gb.y, u11r = gb.z, u11i = gb.w;

#define LANE_COEFFS(hi) \
    const float car = (hi) ? u11r : u00r, cai = (hi) ? u11i : u00i; \
    const float cbr = (hi) ? u10r : u01r, cbi = (hi) ? u10i : u01i;

    // ================= LAYER 2 (M = prefix) =================
    // gate q pairs differ by delta = e_q ^ e_{q+1}; hi = prefix parity p0..pq
    { LOADG(8);  LANE_COEFFS(b4);                lane_gate<24>(re, im, car, cai, cbr, cbi); }
    { LOADG(9);  LANE_COEFFS(b4 ^ b3);           lane_gate<12>(re, im, car, cai, cbr, cbi); }
    { LOADG(10); LANE_COEFFS(b4 ^ b3 ^ b2);      lane_gate<6>(re, im, car, cai, cbr, cbi); }
    { LOADG(11); LANE_COEFFS(b4 ^ b3 ^ b2 ^ b1); lane_gate<3>(re, im, car, cai, cbr, cbi); }
    // q4: partner = (lane^1, r^4); hi = par5 (uniform over regs)
    {
        LOADG(12); LANE_COEFFS(par5);
#pragma unroll
        for (int r = 0; r < 4; ++r) {
            const float a0r = re[r],     a0i = im[r];
            const float a1r = re[r + 4], a1i = im[r + 4];
            const float p0r = dpp1<QP_XOR1>(a1r), p0i = dpp1<QP_XOR1>(a1i);
            const float p1r = dpp1<QP_XOR1>(a0r), p1i = dpp1<QP_XOR1>(a0i);
            re[r]     = car * a0r - cai * a0i + cbr * p0r - cbi * p0i;
            im[r]     = car * a0i + cai * a0r + cbr * p0i + cbi * p0r;
            re[r + 4] = car * a1r - cai * a1i + cbr * p1r - cbi * p1i;
            im[r + 4] = car * a1i + cai * a1r + cbr * p1i + cbi * p1r;
        }
    }
    // q5..q7: in-register, element hi = par5 ^ parity(r & FBITS)
#define REG2_COEFFS() \
    const float c0r = par5 ? u11r : u00r, c0i = par5 ? u11i : u00i; \
    const float d0r = par5 ? u10r : u01r, d0i = par5 ? u10i : u01i; \
    const float c1r = par5 ? u00r : u11r, c1i = par5 ? u00i : u11i; \
    const float d1r = par5 ? u01r : u10r, d1i = par5 ? u01i : u10i;
    { LOADG(13); REG2_COEFFS(); reg_gate<6,4>(re, im, c0r,c0i,d0r,d0i,c1r,c1i,d1r,d1i); }
    { LOADG(14); REG2_COEFFS(); reg_gate<3,6>(re, im, c0r,c0i,d0r,d0i,c1r,c1i,d1r,d1i); }
    { LOADG(15); REG2_COEFFS(); reg_gate<1,7>(re, im, c0r,c0i,d0r,d0i,c1r,c1i,d1r,d1i); }

    // ================= measurement under final M =================
    // M0=p0 M1=p1 M2=p0^p2 M3=p1^p3 M4=p0^p2^p4 M5=p1^p3^p5 M6=p0^p2^p4^p6 M7=p1^p3^p5^p7
    // p0..p4 = lane bits b4..b0 ; p5,p6,p7 = reg bits r2,r1,r0
    float P[8];
#pragma unroll
    for (int r = 0; r < 8; ++r) P[r] = re[r] * re[r] + im[r] * im[r];

    const float t01 = P[0] + P[1], t23 = P[2] + P[3];
    const float t45 = P[4] + P[5], t67 = P[6] + P[7];
    const float A  = (t01 + t23) + (t45 + t67);
    const float B5 = (t01 + t23) - (t45 + t67);                 // (-1)^{r2}
    const float B6 = (t01 - t23) + (t45 - t67);                 // (-1)^{r1}
    const float B7 = (P[0] - P[1]) + (P[2] - P[3])
                   - (P[4] - P[5]) - (P[6] - P[7]);             // (-1)^{r2^r0}

    const bool gOdd  = b3 ^ b1;          // p1^p3
    const bool gEven = b4 ^ b2;          // p0^p2
    const bool gEv0  = gEven ^ b0;       // p0^p2^p4
    float z0 = b4    ? -A  : A;
    float z1 = b3    ? -A  : A;
    float z2 = gEven ? -A  : A;
    float z3 = gOdd  ? -A  : A;
    float z4 = gEv0  ? -A  : A;
    float z5 = gOdd  ? -B5 : B5;
    float z6 = gEv0  ? -B6 : B6;
    float z7 = gOdd  ? -B7 : B7;

    // butterfly over the 32-lane half-wave
#define RED(z) \
    z += dpp1<QP_XOR1>(z); z += dpp1<QP_XOR2>(z); \
    z += dpp1<ROW_ROR4>(z); z += dpp1<ROW_ROR8>(z); \
    z += swz<16>(z);
    RED(z0) RED(z1) RED(z2) RED(z3) RED(z4) RED(z5) RED(z6) RED(z7)
#undef RED

    if (sub < 8) {
        float v = z0;
        v = (sub == 1) ? z1 : v;
        v = (sub == 2) ? z2 : v;
        v = (sub == 3) ? z3 : v;
        v = (sub == 4) ? z4 : v;
        v = (sub == 5) ? z5 : v;
        v = (sub == 6) ? z6 : v;
        v = (sub == 7) ? z7 : v;
        out[sample * 8 + sub] = v;
    }
}

extern "C" void kernel_launch(void* const* d_in, const int* in_sizes, int n_in,
                              void* d_out, int out_size, void* d_ws, size_t ws_size,
                              hipStream_t stream) {
    const float* x     = (const float*)d_in[0];
    const float* theta = (const float*)d_in[1];
    float* out = (float*)d_out;
    const int B = in_sizes[0] / 8;
    const long long threads_total = (long long)B * 32;   // 32 lanes per sample
    const int blocks = (int)((threads_total + 255) / 256);
    hipLaunchKernelGGL(quantum_kernel, dim3(blocks), dim3(256), 0, stream,
                       x, theta, out, B);
}

// Round 7
// 64.348 us; speedup vs baseline: 1.1601x; 1.0065x over previous
//
#include <hip/hip_runtime.h>

#define PI_HALF_F 1.57079632679489661923f

// ---- lane-exchange primitives ----
template<int CTRL>
__device__ __forceinline__ float dpp1(float v) {
    return __int_as_float(__builtin_amdgcn_update_dpp(
        0, __float_as_int(v), CTRL, 0xF, 0xF, true));
}
#define QP_XOR1   0xB1   // quad_perm [1,0,3,2]
#define QP_XOR2   0x4E   // quad_perm [2,3,0,1]
#define QP_XOR3   0x1B   // quad_perm [3,2,1,0]
#define ROW_ROR4  0x124
#define ROW_ROR8  0x128

template<int MASK>
__device__ __forceinline__ float swz(float v) {
    return __int_as_float(__builtin_amdgcn_ds_swizzle(
        __float_as_int(v), (MASK << 10) | 0x1F));
}

// exact xor-MASK exchange within 32-lane halves: DPP intra-quad, DS swizzle >=4
template<int MASK>
__device__ __forceinline__ float XL(float v) {
    if constexpr (MASK == 1)       return dpp1<QP_XOR1>(v);
    else if constexpr (MASK == 2)  return dpp1<QP_XOR2>(v);
    else if constexpr (MASK == 3)  return dpp1<QP_XOR3>(v);
    else                           return swz<MASK>(v);   // 4,6,8,12,16,24
}

__device__ __forceinline__ float xorf(float v, unsigned s) {
    return __int_as_float(__float_as_int(v) ^ (int)s);
}

// ---- cross-lane 2x2 gate on 8 amps, partner = lane ^ MASK ----
// coeffs: self = (car, cai), partner = (cbr, cbi); car/cbi uniform, cai/cbr pre-signed
template<int MASK>
__device__ __forceinline__ void lane_gate(float (&re)[8], float (&im)[8],
                                          float car, float cai, float cbr, float cbi) {
#pragma unroll
    for (int r = 0; r < 8; ++r) {
        const float ar = re[r], ai = im[r];
        const float br = XL<MASK>(ar), bi = XL<MASK>(ai);
        re[r] = car * ar - cai * ai + cbr * br - cbi * bi;
        im[r] = car * ai + cai * ar + cbr * bi + cbi * br;
    }
}

// ---- in-register 2x2 gate: pairs (r, r^MASK); element-hi = parity(r & FBITS)
// Uses conj structure: u11 = conj(u00), u10 = -conj(u01).
// cr = u00r, ci = (hi-base-signed) u00i, dr = (hi-base-signed) u01r, di = u01i.
template<int MASK, int FBITS>
__device__ __forceinline__ void reg_gate(float (&re)[8], float (&im)[8],
        float cr, float ci, float dr, float di) {
    constexpr int MSB = (MASK & 4) ? 4 : (MASK & 2) ? 2 : 1;
#pragma unroll
    for (int r = 0; r < 8; ++r) {
        if (r & MSB) continue;
        const int p = r ^ MASK;
        const bool f = __builtin_popcount(r & FBITS) & 1;  // compile-time
        const float sAi = f ? -ci : ci;   // folds into FMA input modifier
        const float tAr = f ? -dr : dr;
        const float ar = re[r], ai = im[r], br = re[p], bi = im[p];
        re[r] = cr * ar - sAi * ai + tAr * br - di * bi;
        im[r] = cr * ai + sAi * ar + tAr * bi + di * br;
        re[p] = cr * br + sAi * bi - tAr * ar - di * ai;
        im[p] = cr * bi - sAi * br - tAr * ai + di * ar;
    }
}

__global__ __launch_bounds__(256, 8) void quantum_kernel(
    const float* __restrict__ x,
    const float* __restrict__ theta,
    float* __restrict__ out,
    int B)
{
    // ---- per-block: 16 gate rows (u00r,u00i,u01r,u01i) in LDS ----
    __shared__ float4 g4[16];
    const int t = threadIdx.x;
    if (t < 16) {
        const int layer = t >> 3, q = t & 7;
        const float phi = theta[(layer * 8 + q) * 3 + 0];
        const float th  = theta[(layer * 8 + q) * 3 + 1];
        const float om  = theta[(layer * 8 + q) * 3 + 2];
        const float ct = __cosf(0.5f * th), st = __sinf(0.5f * th);
        const float a = 0.5f * (phi + om), b = 0.5f * (phi - om);
        const float ca = __cosf(a), sa = __sinf(a);
        const float cb = __cosf(b), sb = __sinf(b);
        g4[t] = make_float4(ct * ca, -ct * sa, -st * cb, -st * sb);
    }
    __syncthreads();

    const int tid = blockIdx.x * 256 + t;
    const int sample = tid >> 5;       // 32 lanes per sample
    if (sample >= B) return;
    const int sub = t & 31;            // lane bits b4..b0 <-> qubits 0..4

    const bool b4 = (sub >> 4) & 1, b3 = (sub >> 3) & 1, b2 = (sub >> 2) & 1;
    const bool b1 = (sub >> 1) & 1, b0 = sub & 1;

    // per-lane hi-parity sign words (prefix parities of physical bits p0..p4)
    const int y1 = sub ^ (sub >> 1);
    const int y2 = y1 ^ (sub >> 2);
    const int y3 = y2 ^ (sub >> 3);
    const int y4 = y3 ^ (sub >> 4);
    const unsigned s_q8  = (unsigned)(sub & 16) << 27;  // b4
    const unsigned s_q9  = (unsigned)(y1 & 8)  << 28;   // b4^b3
    const unsigned s_q10 = (unsigned)(y2 & 4)  << 29;   // b4^b3^b2
    const unsigned s_q11 = (unsigned)(y3 & 2)  << 30;   // b4^b3^b2^b1
    const unsigned s_par = (unsigned)(y4 & 1)  << 31;   // par5

    // ---- FUSED: encoding RY + ALL of layer-1 Rot -> complex product state ----
    // v0 = u00*c + u01*s ; v1 = u10*c + u11*s = (u00r*s - u01r*c, u01i*c - u00i*s)
    float re[8], im[8];
    {
        const float4* xp = reinterpret_cast<const float4*>(x + sample * 8);
        const float4 xa = xp[0], xb = xp[1];
        const float xs[8] = {xa.x, xa.y, xa.z, xa.w, xb.x, xb.y, xb.z, xb.w};
        float cq[8], sq[8];
#pragma unroll
        for (int q = 0; q < 8; ++q) {
            const float v = fminf(fmaxf(xs[q], -1.0f), 1.0f) * PI_HALF_F;
            cq[q] = __cosf(v);
            sq[q] = __sinf(v);
        }
        float wrr[5], wri[5];
        float v5r[2], v5i[2], v6r[2], v6i[2], v7r[2], v7i[2];
#pragma unroll
        for (int q = 0; q < 8; ++q) {
            const float4 gq = g4[q];
            const float c = cq[q], s = sq[q];
            const float v0r = gq.x * c + gq.z * s, v0i = gq.y * c + gq.w * s;
            const float v1r = gq.x * s - gq.z * c, v1i = gq.w * c - gq.y * s;
            if (q < 5) {
                const bool bit = (sub >> (4 - q)) & 1;
                wrr[q] = bit ? v1r : v0r;
                wri[q] = bit ? v1i : v0i;
            } else if (q == 5) {
                v5r[0] = v0r; v5i[0] = v0i; v5r[1] = v1r; v5i[1] = v1i;
            } else if (q == 6) {
                v6r[0] = v0r; v6i[0] = v0i; v6r[1] = v1r; v6i[1] = v1i;
            } else {
                v7r[0] = v0r; v7i[0] = v0i; v7r[1] = v1r; v7i[1] = v1i;
            }
        }
        float pr = wrr[0], pi_ = wri[0];
#pragma unroll
        for (int q = 1; q < 5; ++q) {
            const float nr = pr * wrr[q] - pi_ * wri[q];
            const float ni = pr * wri[q] + pi_ * wrr[q];
            pr = nr; pi_ = ni;
        }
        float p5r[2], p5i[2];
#pragma unroll
        for (int k = 0; k < 2; ++k) {
            p5r[k] = pr * v5r[k] - pi_ * v5i[k];
            p5i[k] = pr * v5i[k] + pi_ * v5r[k];
        }
        float h67r[4], h67i[4];
#pragma unroll
        for (int k = 0; k < 4; ++k) {
            h67r[k] = v6r[k >> 1] * v7r[k & 1] - v6i[k >> 1] * v7i[k & 1];
            h67i[k] = v6r[k >> 1] * v7i[k & 1] + v6i[k >> 1] * v7r[k & 1];
        }
#pragma unroll
        for (int r = 0; r < 8; ++r) {
            re[r] = p5r[r >> 2] * h67r[r & 3] - p5i[r >> 2] * h67i[r & 3];
            im[r] = p5r[r >> 2] * h67i[r & 3] + p5i[r >> 2] * h67r[r & 3];
        }
    }
    // layer-1 CNOT chain: GF(2) relabel -> zero instructions.

#define LOADG(idx) \
    const float4 gq = g4[idx]; \
    const float u00r = gq.x, u00i = gq.y, u01r = gq.z, u01i = gq.w;

    // lane-gate coeffs via conj structure: self=(u00r, u00i^s), partner=(u01r^s, u01i)
#define LANE_SIGNED(sg) \
    const float car = u00r, cbi = u01i; \
    const float cai = xorf(u00i, sg), cbr = xorf(u01r, sg);

    // ================= LAYER 2 (M = prefix) =================
    { LOADG(8);  LANE_SIGNED(s_q8);  lane_gate<24>(re, im, car, cai, cbr, cbi); }
    { LOADG(9);  LANE_SIGNED(s_q9);  lane_gate<12>(re, im, car, cai, cbr, cbi); }
    { LOADG(10); LANE_SIGNED(s_q10); lane_gate<6>(re, im, car, cai, cbr, cbi); }
    { LOADG(11); LANE_SIGNED(s_q11); lane_gate<3>(re, im, car, cai, cbr, cbi); }
    // q4: partner = (lane^1, r^4); hi = par5 (uniform over regs)
    {
        LOADG(12); LANE_SIGNED(s_par);
#pragma unroll
        for (int r = 0; r < 4; ++r) {
            const float a0r = re[r],     a0i = im[r];
            const float a1r = re[r + 4], a1i = im[r + 4];
            const float p0r = dpp1<QP_XOR1>(a1r), p0i = dpp1<QP_XOR1>(a1i);
            const float p1r = dpp1<QP_XOR1>(a0r), p1i = dpp1<QP_XOR1>(a0i);
            re[r]     = car * a0r - cai * a0i + cbr * p0r - cbi * p0i;
            im[r]     = car * a0i + cai * a0r + cbr * p0i + cbi * p0r;
            re[r + 4] = car * a1r - cai * a1i + cbr * p1r - cbi * p1i;
            im[r + 4] = car * a1i + cai * a1r + cbr * p1i + cbi * p1r;
        }
    }
    // q5..q7: in-register; hi = par5 ^ parity(r & FBITS).
    // Shared par5-signed coefficient pair for all three gates:
    { LOADG(13);
      const float ci2 = xorf(u00i, s_par), dr2 = xorf(u01r, s_par);
      reg_gate<6,4>(re, im, u00r, ci2, dr2, u01i); }
    { LOADG(14);
      const float ci2 = xorf(u00i, s_par), dr2 = xorf(u01r, s_par);
      reg_gate<3,6>(re, im, u00r, ci2, dr2, u01i); }
    { LOADG(15);
      const float ci2 = xorf(u00i, s_par), dr2 = xorf(u01r, s_par);
      reg_gate<1,7>(re, im, u00r, ci2, dr2, u01i); }

    // ================= measurement under final M =================
    // p0..p4 = lane bits b4..b0 ; p5,p6,p7 = reg bits r2,r1,r0
    float P[8];
#pragma unroll
    for (int r = 0; r < 8; ++r) P[r] = re[r] * re[r] + im[r] * im[r];

    const float t01 = P[0] + P[1], t23 = P[2] + P[3];
    const float t45 = P[4] + P[5], t67 = P[6] + P[7];
    const float A  = (t01 + t23) + (t45 + t67);
    const float B5 = (t01 + t23) - (t45 + t67);                 // (-1)^{r2}
    const float B6 = (t01 - t23) + (t45 - t67);                 // (-1)^{r1}
    const float B7 = (P[0] - P[1]) + (P[2] - P[3])
                   - (P[4] - P[5]) - (P[6] - P[7]);             // (-1)^{r2^r0}

    const bool gOdd  = b3 ^ b1;          // p1^p3
    const bool gEven = b4 ^ b2;          // p0^p2
    const bool gEv0  = gEven ^ b0;       // p0^p2^p4
    float z0 = b4    ? -A  : A;
    float z1 = b3    ? -A  : A;
    float z2 = gEven ? -A  : A;
    float z3 = gOdd  ? -A  : A;
    float z4 = gEv0  ? -A  : A;
    float z5 = gOdd  ? -B5 : B5;
    float z6 = gEv0  ? -B6 : B6;
    float z7 = gOdd  ? -B7 : B7;

    // butterfly over the 32-lane half-wave
#define RED(z) \
    z += dpp1<QP_XOR1>(z); z += dpp1<QP_XOR2>(z); \
    z += dpp1<ROW_ROR4>(z); z += dpp1<ROW_ROR8>(z); \
    z += swz<16>(z);
    RED(z0) RED(z1) RED(z2) RED(z3) RED(z4) RED(z5) RED(z6) RED(z7)
#undef RED

    if (sub < 8) {
        float v = z0;
        v = (sub == 1) ? z1 : v;
        v = (sub == 2) ? z2 : v;
        v = (sub == 3) ? z3 : v;
        v = (sub == 4) ? z4 : v;
        v = (sub == 5) ? z5 : v;
        v = (sub == 6) ? z6 : v;
        v = (sub == 7) ? z7 : v;
        out[sample * 8 + sub] = v;
    }
}

extern "C" void kernel_launch(void* const* d_in, const int* in_sizes, int n_in,
                              void* d_out, int out_size, void* d_ws, size_t ws_size,
                              hipStream_t stream) {
    const float* x     = (const float*)d_in[0];
    const float* theta = (const float*)d_in[1];
    float* out = (float*)d_out;
    const int B = in_sizes[0] / 8;
    const long long threads_total = (long long)B * 32;   // 32 lanes per sample
    const int blocks = (int)((threads_total + 255) / 256);
    hipLaunchKernelGGL(quantum_kernel, dim3(blocks), dim3(256), 0, stream,
                       x, theta, out, B);
}